// Round 2
// baseline (667.546 us; speedup 1.0000x reference)
//
#include <hip/hip_runtime.h>

typedef __attribute__((ext_vector_type(4))) float f32x4;
typedef __attribute__((ext_vector_type(8))) short bf16x8;
typedef unsigned short u16;

constexpr int kB = 2, kS = 2048, kD = 1024, kH = 16, kHD = 64, kHID = 3584;
constexpr int kN = kB * kS;  // 4096 tokens

__device__ __forceinline__ u16 f2bf(float f) {
  unsigned u = __float_as_uint(f);
  u = (u + 0x7FFFu + ((u >> 16) & 1u)) >> 16;
  return (u16)u;
}

#define AS1(p) ((const __attribute__((address_space(1))) void*)(p))
#define AS3(p) ((__attribute__((address_space(3))) void*)(p))

// ---------------------------------------------------------------- prep: x+pos, RMSNorm1
__global__ __launch_bounds__(256) void k_prep(
    const float* __restrict__ x, const float* __restrict__ pos,
    const float* __restrict__ w, float* __restrict__ xr, u16* __restrict__ xn) {
  const int n = blockIdx.x, t = threadIdx.x, s = n & (kS - 1);
  float4 a = ((const float4*)(x + (size_t)n * kD))[t];
  float4 p = ((const float4*)(pos + (size_t)s * kD))[t];
  a.x += p.x; a.y += p.y; a.z += p.z; a.w += p.w;
  ((float4*)(xr + (size_t)n * kD))[t] = a;
  float ss = a.x*a.x + a.y*a.y + a.z*a.z + a.w*a.w;
#pragma unroll
  for (int off = 1; off < 64; off <<= 1) ss += __shfl_xor(ss, off);
  __shared__ float red[4];
  if ((t & 63) == 0) red[t >> 6] = ss;
  __syncthreads();
  float rs = rsqrtf((red[0] + red[1] + red[2] + red[3]) * (1.0f / kD) + 1e-6f);
  float4 wv = ((const float4*)w)[t];
  ushort4 o;
  o.x = f2bf(a.x * rs * wv.x); o.y = f2bf(a.y * rs * wv.y);
  o.z = f2bf(a.z * rs * wv.z); o.w = f2bf(a.w * rs * wv.w);
  ((ushort4*)(xn + (size_t)n * kD))[t] = o;
}

// ---------------------------------------------------------------- RMSNorm2 (reads fp32 x2)
__global__ __launch_bounds__(256) void k_rms2(
    const float* __restrict__ xin, const float* __restrict__ w, u16* __restrict__ xn) {
  const int n = blockIdx.x, t = threadIdx.x;
  float4 a = ((const float4*)(xin + (size_t)n * kD))[t];
  float ss = a.x*a.x + a.y*a.y + a.z*a.z + a.w*a.w;
#pragma unroll
  for (int off = 1; off < 64; off <<= 1) ss += __shfl_xor(ss, off);
  __shared__ float red[4];
  if ((t & 63) == 0) red[t >> 6] = ss;
  __syncthreads();
  float rs = rsqrtf((red[0] + red[1] + red[2] + red[3]) * (1.0f / kD) + 1e-6f);
  float4 wv = ((const float4*)w)[t];
  ushort4 o;
  o.x = f2bf(a.x * rs * wv.x); o.y = f2bf(a.y * rs * wv.y);
  o.z = f2bf(a.z * rs * wv.z); o.w = f2bf(a.w * rs * wv.w);
  ((ushort4*)(xn + (size_t)n * kD))[t] = o;
}

// ---------------------------------------------------------------- fp32 -> bf16 convert
__global__ __launch_bounds__(256) void k_cvt(
    const float* __restrict__ src, u16* __restrict__ dst, int n4) {
  int i = blockIdx.x * 256 + threadIdx.x;
  if (i < n4) {
    float4 v = ((const float4*)src)[i];
    ushort4 o;
    o.x = f2bf(v.x); o.y = f2bf(v.y); o.z = f2bf(v.z); o.w = f2bf(v.w);
    ((ushort4*)dst)[i] = o;
  }
}

__global__ __launch_bounds__(256) void k_copy(
    const float* __restrict__ src, float* __restrict__ dst, int n) {
  int i = blockIdx.x * 256 + threadIdx.x;
  if (i < n) dst[i] = src[i];
}

// ---------------------------------------------------------------- GEMM: C = A(bf16,MxK) * B(bf16,NxK)^T + bias
// MODE 0: out bf16 = acc + bias
// MODE 1: out fp32 = acc + bias + extra[idx]   (residual)
// MODE 2: out fp32 = acc + bias
// MODE 3: out bf16 = silu(acc + bias) * extra[idx]
template <int MODE>
__global__ __launch_bounds__(256) void k_gemm(
    const u16* __restrict__ A, const u16* __restrict__ Bw,
    const float* __restrict__ bias, const float* extra,
    void* outp, int M, int N, int K) {
  __shared__ __align__(16) u16 As[128 * 32];
  __shared__ __align__(16) u16 Bs[128 * 32];
  const int tid = threadIdx.x, lane = tid & 63, wv_ = tid >> 6;
  const int lr = lane & 15, lg = lane >> 4;
  const int brow = blockIdx.y * 128, bcol = blockIdx.x * 128;
  const int wr = wv_ >> 1, wc = wv_ & 1;

  const f32x4 zz = {0.f, 0.f, 0.f, 0.f};
  f32x4 acc[4][4];
#pragma unroll
  for (int m = 0; m < 4; m++)
#pragma unroll
    for (int n = 0; n < 4; n++) acc[m][n] = zz;

  for (int kt = 0; kt < K; kt += 32) {
#pragma unroll
    for (int i = 0; i < 2; ++i) {
      const int seg = (i * 4 + wv_) * 64 + lane;
      const int row = seg >> 2, cs = seg & 3;
      __builtin_amdgcn_global_load_lds(AS1(A + (size_t)(brow + row) * K + kt + cs * 8),
                                       AS3((char*)As + (size_t)(i * 4 + wv_) * 1024), 16, 0, 0);
      __builtin_amdgcn_global_load_lds(AS1(Bw + (size_t)(bcol + row) * K + kt + cs * 8),
                                       AS3((char*)Bs + (size_t)(i * 4 + wv_) * 1024), 16, 0, 0);
    }
    __syncthreads();
    bf16x8 af[4], bfr[4];
#pragma unroll
    for (int m = 0; m < 4; m++) af[m] = *(const bf16x8*)&As[(wr * 64 + m * 16 + lr) * 32 + lg * 8];
#pragma unroll
    for (int n = 0; n < 4; n++) bfr[n] = *(const bf16x8*)&Bs[(wc * 64 + n * 16 + lr) * 32 + lg * 8];
#pragma unroll
    for (int m = 0; m < 4; m++)
#pragma unroll
      for (int n = 0; n < 4; n++)
        acc[m][n] = __builtin_amdgcn_mfma_f32_16x16x32_bf16(af[m], bfr[n], acc[m][n], 0, 0, 0);
    __syncthreads();
  }

  // epilogue: C layout col=lane&15, row=(lane>>4)*4+reg  [m89-verified]
#pragma unroll
  for (int m = 0; m < 4; m++) {
    const int row0 = brow + wr * 64 + m * 16 + lg * 4;
#pragma unroll
    for (int n = 0; n < 4; n++) {
      const int col = bcol + wc * 64 + n * 16 + lr;
      const float bv = bias[col];
#pragma unroll
      for (int r = 0; r < 4; r++) {
        const size_t idx = (size_t)(row0 + r) * N + col;
        float v = acc[m][n][r] + bv;
        if (MODE == 0) {
          ((u16*)outp)[idx] = f2bf(v);
        } else if (MODE == 1) {
          ((float*)outp)[idx] = v + extra[idx];
        } else if (MODE == 2) {
          ((float*)outp)[idx] = v;
        } else {
          float h = v / (1.0f + __expf(-v)) * extra[idx];
          ((u16*)outp)[idx] = f2bf(h);
        }
      }
    }
  }
}

// ---------------------------------------------------------------- flash attention (causal)
// grid: (S/64, B*H), 256 threads = 4 waves, each wave owns 16 q rows.
// qkv layout: [token][3072], q at col 0, k at 1024, v at 2048, head h at +h*64.
__global__ __launch_bounds__(256) void k_attn(
    const u16* __restrict__ qkv, u16* __restrict__ attn_o) {
  __shared__ __align__(16) u16 Ks[32 * 64];       // swizzled row-major K tile
  __shared__ __align__(16) u16 Vt[64 * 32];       // transposed + swizzled V tile
  __shared__ __align__(16) u16 Pl[4][16 * 32];    // per-wave P tile (swizzled)

  const int tid = threadIdx.x, lane = tid & 63, w = tid >> 6;
  const int lr = lane & 15, lg = lane >> 4;
  const int qb = blockIdx.x, bh = blockIdx.y;
  const int b = bh >> 4, h = bh & 15;
  const size_t base = (size_t)b * kS;

  // Q fragments (A-frag: row=lr, k = step*32 + lg*8 + j), held in regs
  const int qrow = qb * 64 + w * 16 + lr;
  bf16x8 qf[2];
#pragma unroll
  for (int st = 0; st < 2; st++)
    qf[st] = *(const bf16x8*)&qkv[(base + qrow) * 3072 + h * 64 + st * 32 + lg * 8];

  const f32x4 zz = {0.f, 0.f, 0.f, 0.f};
  f32x4 o_acc[4];
#pragma unroll
  for (int nb = 0; nb < 4; nb++) o_acc[nb] = zz;
  float mrow[4] = {-1e30f, -1e30f, -1e30f, -1e30f};
  float lrow[4] = {0.f, 0.f, 0.f, 0.f};

  const int nt = (qb + 1) * 2;  // kv tiles of 32
  for (int t = 0; t < nt; ++t) {
    __syncthreads();
    {  // stage K tile: 32 rows x 64 cols, 16B seg per thread, XOR swizzle
      const int row = tid >> 3, cs = tid & 7;
      int4 kd = *(const int4*)&qkv[(base + t * 32 + row) * 3072 + 1024 + h * 64 + cs * 8];
      const int bo = (row * 128 + cs * 16) ^ ((row & 7) << 4);
      *(int4*)((char*)Ks + bo) = kd;
    }
    {  // stage V transposed: thread loads 8 elems of one V row, scatters to Vt
      const int kv = tid >> 3, ds0 = (tid & 7) * 8;
      int4 vd = *(const int4*)&qkv[(base + t * 32 + kv) * 3072 + 2048 + h * 64 + ds0];
      const u16* ve = (const u16*)&vd;
#pragma unroll
      for (int j = 0; j < 8; j++) {
        const int d = ds0 + j;
        const int bo = (d * 64 + kv * 2) ^ ((d & 7) << 4);
        *(u16*)((char*)Vt + bo) = ve[j];
      }
    }
    __syncthreads();

    // QK^T: S[16x32] in two 16-col halves
    f32x4 sc[2];
#pragma unroll
    for (int hn = 0; hn < 2; hn++) {
      sc[hn] = zz;
#pragma unroll
      for (int ks = 0; ks < 2; ks++) {
        const int krow = hn * 16 + lr;
        const int bo = (krow * 128 + ks * 64 + lg * 16) ^ ((krow & 7) << 4);
        bf16x8 kf = *(const bf16x8*)((const char*)Ks + bo);
        sc[hn] = __builtin_amdgcn_mfma_f32_16x16x32_bf16(qf[ks], kf, sc[hn], 0, 0, 0);
      }
    }

    // online softmax (rows lg*4+r, cols t*32 + hn*16 + lr)
    float alpha[4];
#pragma unroll
    for (int r = 0; r < 4; r++) {
      const int q = qb * 64 + w * 16 + lg * 4 + r;
      float s0 = sc[0][r] * 0.125f, s1 = sc[1][r] * 0.125f;
      if (t * 32 + lr > q) s0 = -1e30f;
      if (t * 32 + 16 + lr > q) s1 = -1e30f;
      float mx = fmaxf(s0, s1);
#pragma unroll
      for (int off = 1; off < 16; off <<= 1) mx = fmaxf(mx, __shfl_xor(mx, off));
      const float mnew = fmaxf(mrow[r], mx);
      alpha[r] = __expf(mrow[r] - mnew);
      mrow[r] = mnew;
      const float p0 = __expf(s0 - mnew), p1 = __expf(s1 - mnew);
      sc[0][r] = p0; sc[1][r] = p1;
      float ps = p0 + p1;
#pragma unroll
      for (int off = 1; off < 16; off <<= 1) ps += __shfl_xor(ps, off);
      lrow[r] = lrow[r] * alpha[r] + ps;
    }
#pragma unroll
    for (int nb = 0; nb < 4; nb++)
#pragma unroll
      for (int r = 0; r < 4; r++) o_acc[nb][r] *= alpha[r];

    // P -> LDS (bf16, swizzled), then PV
    u16* pw = &Pl[w][0];
#pragma unroll
    for (int hn = 0; hn < 2; hn++)
#pragma unroll
      for (int r = 0; r < 4; r++) {
        const int prow = lg * 4 + r, pcol = hn * 16 + lr;
        const int bo = (prow * 64 + pcol * 2) ^ ((prow & 7) << 4);
        *(u16*)((char*)pw + bo) = f2bf(sc[hn][r]);
      }
    const int pbo = (lr * 64 + lg * 16) ^ ((lr & 7) << 4);
    bf16x8 pf = *(const bf16x8*)((const char*)pw + pbo);
#pragma unroll
    for (int nb = 0; nb < 4; nb++) {
      const int vrow = nb * 16 + lr;
      const int vbo = (vrow * 64 + lg * 16) ^ ((vrow & 7) << 4);
      bf16x8 vf = *(const bf16x8*)((const char*)Vt + vbo);
      o_acc[nb] = __builtin_amdgcn_mfma_f32_16x16x32_bf16(pf, vf, o_acc[nb], 0, 0, 0);
    }
  }

  // epilogue
#pragma unroll
  for (int nb = 0; nb < 4; nb++)
#pragma unroll
    for (int r = 0; r < 4; r++) {
      const int q = qb * 64 + w * 16 + lg * 4 + r;
      const float v = o_acc[nb][r] / lrow[r];
      attn_o[(base + q) * kD + h * 64 + nb * 16 + lr] = f2bf(v);
    }
}

// ---------------------------------------------------------------- workspace layout (bytes)
constexpr size_t OFF_XR   = 0;                                   // fp32 [4096][1024]
constexpr size_t OFF_XN1  = OFF_XR  + (size_t)kN * kD * 4;       // bf16 [4096][1024]
constexpr size_t OFF_XN2  = OFF_XN1 + (size_t)kN * kD * 2;       // bf16 [4096][1024]
constexpr size_t OFF_W    = OFF_XN2 + (size_t)kN * kD * 2;       // weight arena (max 14680064 B)
constexpr size_t OFF_BQKV = OFF_W + 14680064;                    // fp32 [3072]
constexpr size_t OFF_ACT  = OFF_BQKV + 3072 * 4;                 // activation arena
// phase 1: qkv bf16 [4096][3072] @ +0 ; attn_o bf16 [4096][1024] @ +25165824
// phase 2: inout fp32 [4096][3584] @ +0 ; hb bf16 [4096][3584] @ +58720256

extern "C" void kernel_launch(void* const* d_in, const int* in_sizes, int n_in,
                              void* d_out, int out_size, void* d_ws, size_t ws_size,
                              hipStream_t stream) {
  const float* x     = (const float*)d_in[0];
  const float* pos   = (const float*)d_in[1];
  const float* n1w   = (const float*)d_in[2];
  const float* n2w   = (const float*)d_in[3];
  const float* q_w   = (const float*)d_in[4];
  const float* q_b   = (const float*)d_in[5];
  const float* k_w   = (const float*)d_in[6];
  const float* k_b   = (const float*)d_in[7];
  const float* v_w   = (const float*)d_in[8];
  const float* v_b   = (const float*)d_in[9];
  const float* o_w   = (const float*)d_in[10];
  const float* o_b   = (const float*)d_in[11];
  const float* in_w  = (const float*)d_in[12];
  const float* in_b  = (const float*)d_in[13];
  const float* gate_w= (const float*)d_in[14];
  const float* gate_b= (const float*)d_in[15];
  const float* out_w = (const float*)d_in[16];
  const float* out_b = (const float*)d_in[17];
  float* outf = (float*)d_out;
  char* ws = (char*)d_ws;

  float* xr   = (float*)(ws + OFF_XR);
  u16*   xn1  = (u16*)(ws + OFF_XN1);
  u16*   xn2  = (u16*)(ws + OFF_XN2);
  u16*   Warena = (u16*)(ws + OFF_W);
  float* bqkv = (float*)(ws + OFF_BQKV);
  u16*   qkv  = (u16*)(ws + OFF_ACT);
  u16*   attn_o = (u16*)(ws + OFF_ACT + (size_t)kN * 3072 * 2);
  float* inout  = (float*)(ws + OFF_ACT);
  u16*   hb     = (u16*)(ws + OFF_ACT + (size_t)kN * kHID * 4);

  // 1. pos add + RMSNorm1
  k_prep<<<kN, 256, 0, stream>>>(x, pos, n1w, xr, xn1);

  // 2. QKV weights -> bf16 (concat), biases concat
  k_cvt<<<1024, 256, 0, stream>>>(q_w, Warena, 262144);
  k_cvt<<<1024, 256, 0, stream>>>(k_w, Warena + 1048576, 262144);
  k_cvt<<<1024, 256, 0, stream>>>(v_w, Warena + 2097152, 262144);
  k_copy<<<4, 256, 0, stream>>>(q_b, bqkv, 1024);
  k_copy<<<4, 256, 0, stream>>>(k_b, bqkv + 1024, 1024);
  k_copy<<<4, 256, 0, stream>>>(v_b, bqkv + 2048, 1024);

  // 3. QKV projection -> qkv bf16 [4096][3072]
  k_gemm<0><<<dim3(24, 32), 256, 0, stream>>>(xn1, Warena, bqkv, nullptr, qkv, kN, 3072, kD);

  // 4. attention
  k_attn<<<dim3(kS / 64, kB * kH), 256, 0, stream>>>(qkv, attn_o);

  // 5. O projection + residual -> d_out fp32
  k_cvt<<<1024, 256, 0, stream>>>(o_w, Warena, 262144);
  k_gemm<1><<<dim3(8, 32), 256, 0, stream>>>(attn_o, Warena, o_b, xr, outf, kN, kD, kD);

  // 6. RMSNorm2
  k_rms2<<<kN, 256, 0, stream>>>(outf, n2w, xn2);

  // 7. MLP: in GEMM (fp32 out), gate GEMM (silu*in -> bf16)
  k_cvt<<<3584, 256, 0, stream>>>(in_w, Warena, 917504);
  k_cvt<<<3584, 256, 0, stream>>>(gate_w, Warena + 3670016, 917504);
  k_gemm<2><<<dim3(28, 32), 256, 0, stream>>>(xn2, Warena, in_b, nullptr, inout, kN, kHID, kD);
  k_gemm<3><<<dim3(28, 32), 256, 0, stream>>>(xn2, Warena + 3670016, gate_b, inout, hb, kN, kHID, kD);

  // 8. MLP out GEMM + residual -> d_out
  k_cvt<<<3584, 256, 0, stream>>>(out_w, Warena, 917504);
  k_gemm<1><<<dim3(8, 32), 256, 0, stream>>>(hb, Warena, out_b, outf, outf, kN, kD, kHID);
}

// Round 3
// 507.320 us; speedup vs baseline: 1.3158x; 1.3158x over previous
//
#include <hip/hip_runtime.h>

typedef __attribute__((ext_vector_type(4))) float f32x4;
typedef __attribute__((ext_vector_type(8))) short bf16x8;
typedef unsigned short u16;

constexpr int kB = 2, kS = 2048, kD = 1024, kH = 16, kHD = 64, kHID = 3584;
constexpr int kN = kB * kS;  // 4096 tokens

__device__ __forceinline__ u16 f2bf(float f) {
  unsigned u = __float_as_uint(f);
  u = (u + 0x7FFFu + ((u >> 16) & 1u)) >> 16;
  return (u16)u;
}
__device__ __forceinline__ float bf2f(u16 v) {
  return __uint_as_float((unsigned)v << 16);
}

#define AS1(p) ((const __attribute__((address_space(1))) void*)(p))
#define AS3(p) ((__attribute__((address_space(3))) void*)(p))

// ---------------------------------------------------------------- prep: x+pos, RMSNorm1
__global__ __launch_bounds__(256) void k_prep(
    const float* __restrict__ x, const float* __restrict__ pos,
    const float* __restrict__ w, float* __restrict__ xr, u16* __restrict__ xn) {
  const int n = blockIdx.x, t = threadIdx.x, s = n & (kS - 1);
  float4 a = ((const float4*)(x + (size_t)n * kD))[t];
  float4 p = ((const float4*)(pos + (size_t)s * kD))[t];
  a.x += p.x; a.y += p.y; a.z += p.z; a.w += p.w;
  ((float4*)(xr + (size_t)n * kD))[t] = a;
  float ss = a.x*a.x + a.y*a.y + a.z*a.z + a.w*a.w;
#pragma unroll
  for (int off = 1; off < 64; off <<= 1) ss += __shfl_xor(ss, off);
  __shared__ float red[4];
  if ((t & 63) == 0) red[t >> 6] = ss;
  __syncthreads();
  float rs = rsqrtf((red[0] + red[1] + red[2] + red[3]) * (1.0f / kD) + 1e-6f);
  float4 wv = ((const float4*)w)[t];
  ushort4 o;
  o.x = f2bf(a.x * rs * wv.x); o.y = f2bf(a.y * rs * wv.y);
  o.z = f2bf(a.z * rs * wv.z); o.w = f2bf(a.w * rs * wv.w);
  ((ushort4*)(xn + (size_t)n * kD))[t] = o;
}

// ---------------------------------------------------------------- RMSNorm2
__global__ __launch_bounds__(256) void k_rms2(
    const float* __restrict__ xin, const float* __restrict__ w, u16* __restrict__ xn) {
  const int n = blockIdx.x, t = threadIdx.x;
  float4 a = ((const float4*)(xin + (size_t)n * kD))[t];
  float ss = a.x*a.x + a.y*a.y + a.z*a.z + a.w*a.w;
#pragma unroll
  for (int off = 1; off < 64; off <<= 1) ss += __shfl_xor(ss, off);
  __shared__ float red[4];
  if ((t & 63) == 0) red[t >> 6] = ss;
  __syncthreads();
  float rs = rsqrtf((red[0] + red[1] + red[2] + red[3]) * (1.0f / kD) + 1e-6f);
  float4 wv = ((const float4*)w)[t];
  ushort4 o;
  o.x = f2bf(a.x * rs * wv.x); o.y = f2bf(a.y * rs * wv.y);
  o.z = f2bf(a.z * rs * wv.z); o.w = f2bf(a.w * rs * wv.w);
  ((ushort4*)(xn + (size_t)n * kD))[t] = o;
}

// ---------------------------------------------------------------- fused weight prep
// regions in float4 units: q_w/k_w/v_w/o_w = 262144 each, in_w/gate_w/out_w = 917504 each,
// then 768 f4 of bias concat (q_b,k_b,v_b -> bqkv).
__device__ __forceinline__ void cvt4(const float* __restrict__ s, u16* __restrict__ d, int j) {
  float4 v = ((const float4*)s)[j];
  ushort4 o;
  o.x = f2bf(v.x); o.y = f2bf(v.y); o.z = f2bf(v.z); o.w = f2bf(v.w);
  ((ushort4*)d)[j] = o;
}

__global__ __launch_bounds__(256) void k_wprep(
    const float* __restrict__ q_w, const float* __restrict__ k_w,
    const float* __restrict__ v_w, const float* __restrict__ o_w,
    const float* __restrict__ in_w, const float* __restrict__ gate_w,
    const float* __restrict__ out_w,
    const float* __restrict__ q_b, const float* __restrict__ k_b,
    const float* __restrict__ v_b,
    u16* __restrict__ W, float* __restrict__ bqkv) {
  const int i = blockIdx.x * 256 + threadIdx.x;
  if (i < 262144)       cvt4(q_w,    W + 0,        i);
  else if (i < 524288)  cvt4(k_w,    W + 1048576,  i - 262144);
  else if (i < 786432)  cvt4(v_w,    W + 2097152,  i - 524288);
  else if (i < 1048576) cvt4(o_w,    W + 3145728,  i - 786432);
  else if (i < 1966080) cvt4(in_w,   W + 4194304,  i - 1048576);
  else if (i < 2883584) cvt4(gate_w, W + 7864320,  i - 1966080);
  else if (i < 3801088) cvt4(out_w,  W + 11534336, i - 2883584);
  else {
    const int j = i - 3801088;  // 0..767
    const float* src = j < 256 ? q_b : (j < 512 ? k_b : v_b);
    ((float4*)bqkv)[j] = ((const float4*)src)[j & 255];
  }
}

// ---------------------------------------------------------------- GEMM: C = A(bf16,MxK) * B(bf16,NxK)^T + bias
// MODE 0: out bf16 = acc + bias
// MODE 1: out fp32 = acc + bias + f32 extra[idx]   (residual)
// MODE 3: out bf16 = silu(acc + bias) * bf16 extra[idx]
template <int MODE, int BM>
__global__ __launch_bounds__(256) void k_gemm(
    const u16* __restrict__ A, const u16* __restrict__ Bw,
    const float* __restrict__ bias, const void* extra,
    void* outp, int M, int N, int K) {
  constexpr int ASEG = BM / 16;      // 1024B segments in A tile
  constexpr int NSEG = ASEG + 8;
  constexpr int WROWS = BM / 2;
  constexpr int MF = BM / 32;        // m-frags per wave
  __shared__ __align__(16) u16 As[BM * 32];
  __shared__ __align__(16) u16 Bs[128 * 32];
  const int tid = threadIdx.x, lane = tid & 63, wv_ = tid >> 6;
  const int lr = lane & 15, lg = lane >> 4;
  const int brow = blockIdx.y * BM, bcol = blockIdx.x * 128;
  const int wr = wv_ >> 1, wc = wv_ & 1;

  const f32x4 zz = {0.f, 0.f, 0.f, 0.f};
  f32x4 acc[MF][4];
#pragma unroll
  for (int m = 0; m < MF; m++)
#pragma unroll
    for (int n = 0; n < 4; n++) acc[m][n] = zz;

  for (int kt = 0; kt < K; kt += 32) {
#pragma unroll
    for (int i = 0; i < NSEG / 4; ++i) {
      const int seg = i * 4 + wv_;
      const int rsub = (seg < ASEG) ? seg : seg - ASEG;
      const int row = rsub * 16 + (lane >> 2), cs = lane & 3;
      if (seg < ASEG) {
        __builtin_amdgcn_global_load_lds(AS1(A + (size_t)(brow + row) * K + kt + cs * 8),
                                         AS3((char*)As + (size_t)seg * 1024), 16, 0, 0);
      } else {
        __builtin_amdgcn_global_load_lds(AS1(Bw + (size_t)(bcol + row) * K + kt + cs * 8),
                                         AS3((char*)Bs + (size_t)(seg - ASEG) * 1024), 16, 0, 0);
      }
    }
    __syncthreads();
    bf16x8 af[MF], bfr[4];
#pragma unroll
    for (int m = 0; m < MF; m++) af[m] = *(const bf16x8*)&As[(wr * WROWS + m * 16 + lr) * 32 + lg * 8];
#pragma unroll
    for (int n = 0; n < 4; n++) bfr[n] = *(const bf16x8*)&Bs[(wc * 64 + n * 16 + lr) * 32 + lg * 8];
#pragma unroll
    for (int m = 0; m < MF; m++)
#pragma unroll
      for (int n = 0; n < 4; n++)
        acc[m][n] = __builtin_amdgcn_mfma_f32_16x16x32_bf16(af[m], bfr[n], acc[m][n], 0, 0, 0);
    __syncthreads();
  }

  // epilogue: C layout col=lane&15, row=(lane>>4)*4+reg  [m89-verified]
#pragma unroll
  for (int m = 0; m < MF; m++) {
    const int row0 = brow + wr * WROWS + m * 16 + lg * 4;
#pragma unroll
    for (int n = 0; n < 4; n++) {
      const int col = bcol + wc * 64 + n * 16 + lr;
      const float bv = bias[col];
#pragma unroll
      for (int r = 0; r < 4; r++) {
        const size_t idx = (size_t)(row0 + r) * N + col;
        float v = acc[m][n][r] + bv;
        if (MODE == 0) {
          ((u16*)outp)[idx] = f2bf(v);
        } else if (MODE == 1) {
          ((float*)outp)[idx] = v + ((const float*)extra)[idx];
        } else {
          float g = v / (1.0f + __expf(-v));
          ((u16*)outp)[idx] = f2bf(g * bf2f(((const u16*)extra)[idx]));
        }
      }
    }
  }
}

// ---------------------------------------------------------------- flash attention (causal, paired q-blocks)
// grid: (16, B*H). Block p handles q-blocks {p, 31-p} (64 rows each) over ONE shared
// KV stream of 64-wide tiles: uniform 33 tile-computes per block. 256 thr = 4 waves,
// wave owns 16 q rows of each q-block. T14 async-split staging (issue early/commit late).
__global__ __launch_bounds__(256) void k_attn(
    const u16* __restrict__ qkv, u16* __restrict__ attn_o) {
  __shared__ __align__(16) u16 Ks[64 * 64];    // [kv][d]  byte = kv*128 + d*2   ^ ((kv&7)<<4)
  __shared__ __align__(16) u16 Vt[64 * 64];    // [d][kv]  byte = d*128 + kv*2   ^ ((d&7)<<4)
  __shared__ __align__(16) u16 Pl[4][16 * 64]; // [q][k]   byte = q*128 + k*2    ^ ((q&7)<<4)

  const int tid = threadIdx.x, lane = tid & 63, w = tid >> 6;
  const int lr = lane & 15, lg = lane >> 4;
  const int p = blockIdx.x, bh = blockIdx.y;
  const int b = bh >> 4, h = bh & 15;
  const int qbL = p, qbH = 31 - p;
  const size_t base = (size_t)b * kS;
  const f32x4 zz = {0.f, 0.f, 0.f, 0.f};

  // Q fragments for both q-blocks (A-frag: row=lr, k=ks*32+lg*8+j)
  bf16x8 qfL[2], qfH[2];
#pragma unroll
  for (int ks = 0; ks < 2; ks++) {
    qfL[ks] = *(const bf16x8*)&qkv[(base + qbL * 64 + w * 16 + lr) * 3072 + h * 64 + ks * 32 + lg * 8];
    qfH[ks] = *(const bf16x8*)&qkv[(base + qbH * 64 + w * 16 + lr) * 3072 + h * 64 + ks * 32 + lg * 8];
  }

  f32x4 oL[4], oH[4];
  float mL[4], lLr[4], mH[4], lHr[4];
#pragma unroll
  for (int nb = 0; nb < 4; nb++) { oL[nb] = zz; oH[nb] = zz; }
#pragma unroll
  for (int r = 0; r < 4; r++) { mL[r] = -1e30f; mH[r] = -1e30f; lLr[r] = 0.f; lHr[r] = 0.f; }

  // staging assignment: thread -> kv row (tid>>2), 16-col chunk ((tid&3)*16)
  const int srow = tid >> 2, scol = (tid & 3) * 16;
  int4 kr0, kr1, vr0, vr1;
  auto issue = [&](int t) {
    const size_t rowb = (base + t * 64 + srow) * 3072 + h * 64;
    kr0 = *(const int4*)&qkv[rowb + 1024 + scol];
    kr1 = *(const int4*)&qkv[rowb + 1024 + scol + 8];
    vr0 = *(const int4*)&qkv[rowb + 2048 + scol];
    vr1 = *(const int4*)&qkv[rowb + 2048 + scol + 8];
  };
  auto commit = [&]() {
    const int bo0 = (srow * 128 + scol * 2) ^ ((srow & 7) << 4);
    const int bo1 = (srow * 128 + scol * 2 + 16) ^ ((srow & 7) << 4);
    *(int4*)((char*)Ks + bo0) = kr0;
    *(int4*)((char*)Ks + bo1) = kr1;
    const u16* ve0 = (const u16*)&vr0;
    const u16* ve1 = (const u16*)&vr1;
#pragma unroll
    for (int j = 0; j < 8; j++) {
      const int d0 = scol + j;
      *(u16*)((char*)Vt + ((d0 * 128 + srow * 2) ^ ((d0 & 7) << 4))) = ve0[j];
      const int d1 = scol + 8 + j;
      *(u16*)((char*)Vt + ((d1 * 128 + srow * 2) ^ ((d1 & 7) << 4))) = ve1[j];
    }
  };

  auto compute = [&](const bf16x8* qf, f32x4* oacc, float* mrow, float* lrow,
                     int qb, int t, bool masked) {
    f32x4 sc[4];
#pragma unroll
    for (int hn = 0; hn < 4; hn++) sc[hn] = zz;
#pragma unroll
    for (int hn = 0; hn < 4; hn++) {
      const int krow = hn * 16 + lr;
#pragma unroll
      for (int ks = 0; ks < 2; ks++) {
        const int bo = (krow * 128 + (ks * 32 + lg * 8) * 2) ^ ((krow & 7) << 4);
        bf16x8 kf = *(const bf16x8*)((const char*)Ks + bo);
        sc[hn] = __builtin_amdgcn_mfma_f32_16x16x32_bf16(qf[ks], kf, sc[hn], 0, 0, 0);
      }
    }
    float alpha[4];
#pragma unroll
    for (int r = 0; r < 4; r++) {
      const int qa = qb * 64 + w * 16 + lg * 4 + r;
      float s0 = sc[0][r] * 0.125f, s1 = sc[1][r] * 0.125f;
      float s2 = sc[2][r] * 0.125f, s3 = sc[3][r] * 0.125f;
      if (masked) {
        if (t * 64 + lr > qa) s0 = -1e30f;
        if (t * 64 + 16 + lr > qa) s1 = -1e30f;
        if (t * 64 + 32 + lr > qa) s2 = -1e30f;
        if (t * 64 + 48 + lr > qa) s3 = -1e30f;
      }
      float mx = fmaxf(fmaxf(s0, s1), fmaxf(s2, s3));
#pragma unroll
      for (int off = 1; off < 16; off <<= 1) mx = fmaxf(mx, __shfl_xor(mx, off));
      const float mnew = fmaxf(mrow[r], mx);
      alpha[r] = __expf(mrow[r] - mnew);
      mrow[r] = mnew;
      s0 = __expf(s0 - mnew); s1 = __expf(s1 - mnew);
      s2 = __expf(s2 - mnew); s3 = __expf(s3 - mnew);
      sc[0][r] = s0; sc[1][r] = s1; sc[2][r] = s2; sc[3][r] = s3;
      float ps = (s0 + s1) + (s2 + s3);
#pragma unroll
      for (int off = 1; off < 16; off <<= 1) ps += __shfl_xor(ps, off);
      lrow[r] = lrow[r] * alpha[r] + ps;
    }
#pragma unroll
    for (int nb = 0; nb < 4; nb++)
#pragma unroll
      for (int r = 0; r < 4; r++) oacc[nb][r] *= alpha[r];
    // P -> per-wave LDS (bf16), then PV
    char* pw = (char*)&Pl[w][0];
#pragma unroll
    for (int hn = 0; hn < 4; hn++)
#pragma unroll
      for (int r = 0; r < 4; r++) {
        const int prow = lg * 4 + r, pcol = hn * 16 + lr;
        *(u16*)(pw + ((prow * 128 + pcol * 2) ^ ((prow & 7) << 4))) = f2bf(sc[hn][r]);
      }
    bf16x8 pf[2];
#pragma unroll
    for (int ks = 0; ks < 2; ks++)
      pf[ks] = *(const bf16x8*)((const char*)pw + ((lr * 128 + (ks * 32 + lg * 8) * 2) ^ ((lr & 7) << 4)));
#pragma unroll
    for (int nb = 0; nb < 4; nb++) {
      const int vrow = nb * 16 + lr;
#pragma unroll
      for (int ks = 0; ks < 2; ks++) {
        const int bo = (vrow * 128 + (ks * 32 + lg * 8) * 2) ^ ((vrow & 7) << 4);
        bf16x8 vf = *(const bf16x8*)((const char*)Vt + bo);
        oacc[nb] = __builtin_amdgcn_mfma_f32_16x16x32_bf16(pf[ks], vf, oacc[nb], 0, 0, 0);
      }
    }
  };

  const int ntS = qbH + 1;  // staged tiles 0..qbH
  issue(0);
  commit();
  __syncthreads();
  for (int t = 0; t < ntS; ++t) {
    const bool haveNext = (t + 1 < ntS);
    if (haveNext) issue(t + 1);           // loads in flight across compute (T14)
    compute(qfH, oH, mH, lHr, qbH, t, t == qbH);
    if (t <= qbL) compute(qfL, oL, mL, lLr, qbL, t, t == qbL);
    __syncthreads();                      // everyone done reading tile t
    if (haveNext) commit();               // vmcnt wait lands here, not before compute
    __syncthreads();                      // tile t+1 ready
  }

  auto epi = [&](f32x4* oacc, float* lrow, int qb) {
#pragma unroll
    for (int nb = 0; nb < 4; nb++)
#pragma unroll
      for (int r = 0; r < 4; r++) {
        const int q = qb * 64 + w * 16 + lg * 4 + r;
        attn_o[(base + q) * kD + h * 64 + nb * 16 + lr] = f2bf(oacc[nb][r] / lrow[r]);
      }
  };
  epi(oH, lHr, qbH);
  epi(oL, lLr, qbL);
}

// ---------------------------------------------------------------- workspace layout (bytes)
constexpr size_t OFF_XR   = 0;                                   // fp32 [4096][1024]
constexpr size_t OFF_XN1  = OFF_XR  + (size_t)kN * kD * 4;       // bf16 [4096][1024]
constexpr size_t OFF_XN2  = OFF_XN1 + (size_t)kN * kD * 2;       // bf16 [4096][1024]
constexpr size_t OFF_W    = OFF_XN2 + (size_t)kN * kD * 2;       // bf16 weight arena (15204352 u16)
constexpr size_t OFF_BQKV = OFF_W + 15204352ull * 2;             // fp32 [3072]
constexpr size_t OFF_ACT  = OFF_BQKV + 3072 * 4;                 // activation arena
// phase 1: qkv bf16 [4096][3072] @ +0 ; attn_o bf16 [4096][1024] @ +25165824
// phase 2: inout bf16 [4096][3584] @ +0 ; hb bf16 [4096][3584] @ +29360128

extern "C" void kernel_launch(void* const* d_in, const int* in_sizes, int n_in,
                              void* d_out, int out_size, void* d_ws, size_t ws_size,
                              hipStream_t stream) {
  const float* x     = (const float*)d_in[0];
  const float* pos   = (const float*)d_in[1];
  const float* n1w   = (const float*)d_in[2];
  const float* n2w   = (const float*)d_in[3];
  const float* q_w   = (const float*)d_in[4];
  const float* q_b   = (const float*)d_in[5];
  const float* k_w   = (const float*)d_in[6];
  const float* k_b   = (const float*)d_in[7];
  const float* v_w   = (const float*)d_in[8];
  const float* v_b   = (const float*)d_in[9];
  const float* o_w   = (const float*)d_in[10];
  const float* o_b   = (const float*)d_in[11];
  const float* in_w  = (const float*)d_in[12];
  const float* in_b  = (const float*)d_in[13];
  const float* gate_w= (const float*)d_in[14];
  const float* gate_b= (const float*)d_in[15];
  const float* out_w = (const float*)d_in[16];
  const float* out_b = (const float*)d_in[17];
  float* outf = (float*)d_out;
  char* ws = (char*)d_ws;

  float* xr   = (float*)(ws + OFF_XR);
  u16*   xn1  = (u16*)(ws + OFF_XN1);
  u16*   xn2  = (u16*)(ws + OFF_XN2);
  u16*   W    = (u16*)(ws + OFF_W);
  float* bqkv = (float*)(ws + OFF_BQKV);
  u16*   qkv  = (u16*)(ws + OFF_ACT);
  u16*   attn_o = (u16*)(ws + OFF_ACT + (size_t)kN * 3072 * 2);
  u16*   inoutb = (u16*)(ws + OFF_ACT);
  u16*   hb     = (u16*)(ws + OFF_ACT + (size_t)kN * kHID * 2);

  // weight arena offsets (u16)
  u16* Wq   = W + 0;
  u16* Wo   = W + 3145728;
  u16* Win  = W + 4194304;
  u16* Wg   = W + 7864320;
  u16* Wout = W + 11534336;

  // 1. pos add + RMSNorm1 ; fused weight conversion
  k_prep<<<kN, 256, 0, stream>>>(x, pos, n1w, xr, xn1);
  k_wprep<<<14851, 256, 0, stream>>>(q_w, k_w, v_w, o_w, in_w, gate_w, out_w,
                                     q_b, k_b, v_b, W, bqkv);

  // 2. QKV projection -> qkv bf16 [4096][3072]
  k_gemm<0, 128><<<dim3(24, 32), 256, 0, stream>>>(xn1, Wq, bqkv, nullptr, qkv, kN, 3072, kD);

  // 3. attention (paired causal blocks)
  k_attn<<<dim3(16, kB * kH), 256, 0, stream>>>(qkv, attn_o);

  // 4. O projection + residual -> d_out fp32
  k_gemm<1, 64><<<dim3(8, 64), 256, 0, stream>>>(attn_o, Wo, o_b, xr, outf, kN, kD, kD);

  // 5. RMSNorm2
  k_rms2<<<kN, 256, 0, stream>>>(outf, n2w, xn2);

  // 6. MLP: in GEMM (bf16 out), gate GEMM (silu*in -> bf16)
  k_gemm<0, 128><<<dim3(28, 32), 256, 0, stream>>>(xn2, Win, in_b, nullptr, inoutb, kN, kHID, kD);
  k_gemm<3, 128><<<dim3(28, 32), 256, 0, stream>>>(xn2, Wg, gate_b, inoutb, hb, kN, kHID, kD);

  // 7. MLP out GEMM + residual -> d_out
  k_gemm<1, 64><<<dim3(8, 64), 256, 0, stream>>>(hb, Wout, out_b, outf, outf, kN, kD, kHID);
}